// Round 13
// baseline (6416.190 us; speedup 1.0000x reference)
//
#include <hip/hip_runtime.h>
#include <math.h>
#include <stdint.h>

#define T_FRAMES 256
#define BATCH    64
#define NH       1024
#define NG       3072   // 3*NH
#define NMELS    80
#define FCD      256

// ---- persistent GRU geometry ----
#define NGRP   4                  // batch groups
#define GB     16                 // batches per group (MFMA N)
#define JBLK   16                 // j's per block (MFMA M)
#define NBLK_G 64                 // blocks per group = NH/JBLK
#define NBLK   (NGRP * NBLK_G)    // 256 blocks = 1/CU
#define WAVES  8
#define KSL    (NH / WAVES)       // 128 k per wave
#define KTW    (KSL / 32)         // 4 ktiles per wave

typedef __bf16 bf16x8 __attribute__((ext_vector_type(8)));
typedef __bf16 bf16x4 __attribute__((ext_vector_type(4)));
typedef float  f32x4  __attribute__((ext_vector_type(4)));

// IC-coherent access (sc0 sc1): bypass L1/L2, serialize at Infinity Cache.
__device__ __forceinline__ uint4 ld_b128_coh(const uint32_t* p) {
  uint4 r;
  asm volatile("global_load_dwordx4 %0, %1, off sc0 sc1"
               : "=v"(r) : "v"(p) : "memory");
  return r;
}
__device__ __forceinline__ uint32_t ld_b32_coh(const uint32_t* p) {
  uint32_t r;
  asm volatile("global_load_dword %0, %1, off sc0 sc1\n\ts_waitcnt vmcnt(0)"
               : "=v"(r) : "v"(p) : "memory");
  return r;
}
__device__ __forceinline__ void st_b32_coh(uint32_t* p, uint32_t v) {
  asm volatile("global_store_dword %0, %1, off sc0 sc1"
               :: "v"(p), "v"(v) : "memory");
}

// global -> LDS direct copy, 16B per lane
__device__ __forceinline__ void gload16(const void* g, void* l) {
  __builtin_amdgcn_global_load_lds(
      (const __attribute__((address_space(1))) void*)g,
      (__attribute__((address_space(3))) void*)l, 16, 0, 0);
}

// ---------------------------------------------------------------------------
__global__ __launch_bounds__(256) void k_transpose_x(
    const float* __restrict__ x, float* __restrict__ xT) {
  int t = blockIdx.x;
  __shared__ float tile[BATCH][NMELS + 1];
  for (int idx = threadIdx.x; idx < BATCH * NMELS; idx += 256) {
    int b = idx / NMELS, i = idx % NMELS;
    tile[b][i] = x[((size_t)b * T_FRAMES + t) * NMELS + i];
  }
  __syncthreads();
  for (int idx = threadIdx.x; idx < BATCH * NMELS; idx += 256) {
    int i = idx / BATCH, b = idx % BATCH;
    xT[((size_t)t * NMELS + i) * BATCH + b] = tile[b][i];
  }
}

// ---------------------------------------------------------------------------
__global__ __launch_bounds__(256) void k_wconv(
    const float* __restrict__ W, __bf16* __restrict__ hi,
    __bf16* __restrict__ lo) {
  size_t i = ((size_t)blockIdx.x * 256 + threadIdx.x) * 4;
  float4 w = *(const float4*)&W[i];
  float f[4] = {w.x, w.y, w.z, w.w};
  bf16x4 H, L;
#pragma unroll
  for (int e = 0; e < 4; ++e) {
    __bf16 hv = (__bf16)f[e];
    H[e] = hv;
    L[e] = (__bf16)(f[e] - (float)hv);
  }
  *(bf16x4*)&hi[i] = H;
  *(bf16x4*)&lo[i] = L;
}

// ---------------------------------------------------------------------------
// fp32 xp GEMM (layer 0 only, K=NMELS)
__global__ __launch_bounds__(256) void k_gemm_xp(
    const float* __restrict__ A, const float* __restrict__ W,
    const float* __restrict__ bias, float* __restrict__ xp, int K, int t0) {
  int ty = blockIdx.y;
  int t  = t0 + ty;
  int g0 = blockIdx.x * 64;
  __shared__ float As[16][64];
  __shared__ float Bs[16][64];

  int tid = threadIdx.x;
  int b0 = (tid & 15) * 4;
  int gq = tid >> 4;
  int ar = tid >> 4;
  int ac = (tid & 15) * 4;
  int bg = tid & 63;
  int bk = (tid >> 6) * 4;

  float acc[4][4] = {{0.f}};
  const float* At = A + (size_t)t * K * BATCH;

  for (int k0 = 0; k0 < K; k0 += 16) {
    *(float4*)&As[ar][ac] = *(const float4*)&At[(size_t)(k0 + ar) * BATCH + ac];
    float4 w = *(const float4*)&W[(size_t)(g0 + bg) * K + k0 + bk];
    Bs[bk + 0][bg] = w.x; Bs[bk + 1][bg] = w.y;
    Bs[bk + 2][bg] = w.z; Bs[bk + 3][bg] = w.w;
    __syncthreads();
#pragma unroll
    for (int kt = 0; kt < 16; ++kt) {
      const float4 a  = *(const float4*)&As[kt][b0];
      const float4 g4 = *(const float4*)&Bs[kt][gq * 4];
      const float av[4] = {a.x, a.y, a.z, a.w};
      const float gv[4] = {g4.x, g4.y, g4.z, g4.w};
#pragma unroll
      for (int gi = 0; gi < 4; ++gi)
#pragma unroll
        for (int bj = 0; bj < 4; ++bj)
          acc[gi][bj] = fmaf(gv[gi], av[bj], acc[gi][bj]);
    }
    __syncthreads();
  }
#pragma unroll
  for (int gi = 0; gi < 4; ++gi) {
    int g = g0 + gq * 4 + gi;
    float bv = bias[g];
    float4 o = make_float4(acc[gi][0] + bv, acc[gi][1] + bv,
                           acc[gi][2] + bv, acc[gi][3] + bv);
    *(float4*)&xp[((size_t)ty * NG + g) * BATCH + b0] = o;
  }
}

// ---------------------------------------------------------------------------
// Tiled MFMA xp GEMM (layers 1,2) — unchanged (verified rounds 9-12).
__global__ __launch_bounds__(256, 2) void k_gemm_mfma2(
    const __bf16* __restrict__ Whi, const __bf16* __restrict__ Wlo,
    const __bf16* __restrict__ Ahi, const __bf16* __restrict__ Alo,
    const float* __restrict__ bias, float* __restrict__ xp) {
  __shared__ __bf16 lds[4][128][64];   // 64 KB
  const int tid = threadIdx.x;
  const int l   = tid & 63;
  const int wv  = tid >> 6;

  int flat  = blockIdx.y * gridDim.x + blockIdx.x;
  int total = gridDim.x * gridDim.y;
  if ((total & 7) == 0) flat = (flat & 7) * (total >> 3) + (flat >> 3);
  const int m0 = (flat % gridDim.x) * 128;
  const int n0 = (flat / gridDim.x) * 128;

  const int wm = (wv & 1) * 64;
  const int wn = (wv >> 1) * 64;

  const int srow = l >> 3;
  const int xcol = ((l & 7) ^ srow) * 8;
  const __bf16* sbase;
  if      (wv == 0) sbase = Whi + (size_t)m0 * NH;
  else if (wv == 1) sbase = Wlo + (size_t)m0 * NH;
  else if (wv == 2) sbase = Ahi + (size_t)n0 * NH;
  else              sbase = Alo + (size_t)n0 * NH;
  const __bf16* ssrc = sbase + (size_t)srow * NH + xcol;

  f32x4 acc[4][4];
#pragma unroll
  for (int mf = 0; mf < 4; ++mf)
#pragma unroll
    for (int nf = 0; nf < 4; ++nf) acc[mf][nf] = (f32x4){0.f, 0.f, 0.f, 0.f};

  for (int k0 = 0; k0 < NH; k0 += 64) {
#pragma unroll
    for (int c = 0; c < 16; ++c)
      gload16(ssrc + (size_t)(c * 8) * NH + k0, &lds[wv][c * 8][0]);
    __syncthreads();

#pragma unroll
    for (int ksub = 0; ksub < 2; ++ksub) {
      const int colr = (((l >> 4) + ksub * 4) ^ (l & 7)) * 8;
      bf16x8 wfh[4], wfl[4], afh[4], afl[4];
#pragma unroll
      for (int mf = 0; mf < 4; ++mf) {
        const int row = wm + mf * 16 + (l & 15);
        wfh[mf] = *(const bf16x8*)&lds[0][row][colr];
        wfl[mf] = *(const bf16x8*)&lds[1][row][colr];
      }
#pragma unroll
      for (int nf = 0; nf < 4; ++nf) {
        const int row = wn + nf * 16 + (l & 15);
        afh[nf] = *(const bf16x8*)&lds[2][row][colr];
        afl[nf] = *(const bf16x8*)&lds[3][row][colr];
      }
#pragma unroll
      for (int mf = 0; mf < 4; ++mf)
#pragma unroll
        for (int nf = 0; nf < 4; ++nf) {
          acc[mf][nf] = __builtin_amdgcn_mfma_f32_16x16x32_bf16(wfh[mf], afh[nf], acc[mf][nf], 0, 0, 0);
          acc[mf][nf] = __builtin_amdgcn_mfma_f32_16x16x32_bf16(wfh[mf], afl[nf], acc[mf][nf], 0, 0, 0);
          acc[mf][nf] = __builtin_amdgcn_mfma_f32_16x16x32_bf16(wfl[mf], afh[nf], acc[mf][nf], 0, 0, 0);
        }
    }
    __syncthreads();
  }

  const int cr = l >> 4;
  const int cc = l & 15;
#pragma unroll
  for (int mf = 0; mf < 4; ++mf) {
#pragma unroll
    for (int q = 0; q < 4; ++q) {
      const int g = m0 + wm + mf * 16 + cr * 4 + q;
      const float bv = bias[g];
#pragma unroll
      for (int nf = 0; nf < 4; ++nf) {
        const int n = n0 + wn + nf * 16 + cc;
        xp[((size_t)(n >> 6) * NG + g) * BATCH + (n & 63)] =
            acc[mf][nf][q] + bv;
      }
    }
  }
}

// ---------------------------------------------------------------------------
// Persistent MFMA GRU layer — r9 protocol with role-separated waves:
//   poller  = wave 7 (pure-MFMA wave, clean vmcnt queue -> cheap poll)
//   publish = wave 4 lane 0 (tid 256; never polls, flag store un-drained)
//   gating  = waves 0-3 (hsp store + per-wave vmcnt(0); act stores fly)
//   part[]  = r9 exact layout [8][3][16][16] (reads 2-way free)
// Protocol per step t: wave7 polls 64 flags >= i; __syncthreads; all waves
// load h(t-1) frags (IC, vmcnt0); MFMA; barrier1; gating -> hsp store,
// per-wave drain, act stores fly; lgkm-barrier2; tid256 publishes flg=i+1.
__global__ __launch_bounds__(512, 1) void k_gru_layer(
    const float* __restrict__ xp,     // [Tc][NG][BATCH], frame t0 first
    const float* __restrict__ whh,    // [NG][NH]
    const float* __restrict__ bhh,    // [NG]
    __bf16* __restrict__ ahi,         // [T][BATCH][NH] h hi plane
    __bf16* __restrict__ alo,         // [T][BATCH][NH] h lo plane
    uint32_t* __restrict__ hsp,       // [2][NGRP][GB][NH] packed u32
    uint32_t* __restrict__ flg,       // [NGRP][64] step-completion flags
    int t0, int tEnd) {
  const int tid = threadIdx.x;
  const int l   = tid & 63;
  const int wv  = tid >> 6;
  const int grp    = (blockIdx.x & 7) >> 1;
  const int blk_in = (blockIdx.x >> 3) * 2 + (blockIdx.x & 1);
  const int j0 = blk_in * JBLK;
  const int n0 = grp * GB;

  __shared__ uint32_t wHs[3 * WAVES * KTW * 64 * 4];   // 96 KB hi fragments
  __shared__ float part[WAVES][3][JBLK][GB];           // r9 layout

  // ---- stage weights: hi -> LDS fragment slots, lo -> VGPRs ----
  const int row_j = j0 + (l & 15);
  const int kbase = wv * KSL + (l >> 4) * 8;
  bf16x8 wlo[3][KTW];
#pragma unroll
  for (int g = 0; g < 3; ++g) {
#pragma unroll
    for (int kt = 0; kt < KTW; ++kt) {
      const float* wp8 = whh + (size_t)(g * NH + row_j) * NH + kbase + kt * 32;
      float4 w0 = *(const float4*)wp8;
      float4 w1 = *(const float4*)(wp8 + 4);
      float f[8] = {w0.x, w0.y, w0.z, w0.w, w1.x, w1.y, w1.z, w1.w};
      bf16x8 hi, lo;
#pragma unroll
      for (int e = 0; e < 8; ++e) {
        __bf16 hv = (__bf16)f[e];
        hi[e] = hv;
        lo[e] = (__bf16)(f[e] - (float)hv);
      }
      *(bf16x8*)&wHs[(((g * WAVES + wv) * KTW + kt) * 64 + l) * 4] = hi;
      wlo[g][kt] = lo;
    }
  }

  const int jl = tid >> 4;
  const int b  = tid & 15;
  const int j  = j0 + (jl & 15);
  float hprev = 0.f, bhr = 0.f, bhz = 0.f, bhn = 0.f;
  if (tid < 256) {
    if (t0 > 0) {
      const size_t po = ((size_t)(t0 - 1) * BATCH + n0 + b) * NH + j;
      hprev = (float)ahi[po] + (float)alo[po];
    }
    bhr = bhh[j]; bhz = bhh[NH + j]; bhn = bhh[2 * NH + j];
  }
  __syncthreads();

  const uint32_t SEL_HI = 0x07060302u;
  const uint32_t SEL_LO = 0x05040100u;

  for (int t = t0, i = 0; t < tEnd; ++t, ++i) {
    const int rpar = (t + 1) & 1;   // parity holding h(t-1)
    const int wpar = t & 1;         // parity receiving h(t)

    // early xp loads (plain, L2/HBM) — overlap with poll + h loads
    float xr = 0.f, xz = 0.f, xn = 0.f;
    if (tid < 256) {
      const float* xpt = xp + (size_t)(t - t0) * NG * BATCH;
      xr = xpt[(size_t)(0 * NH + j) * BATCH + n0 + b];
      xz = xpt[(size_t)(1 * NH + j) * BATCH + n0 + b];
      xn = xpt[(size_t)(2 * NH + j) * BATCH + n0 + b];
    }

    // ---- poll (wave 7: clean vmcnt queue — no stores ever outstanding) ----
    if (i > 0) {
      if (wv == 7) {
        const uint32_t tgt = (uint32_t)i;
        while (true) {
          uint32_t f = ld_b32_coh(flg + grp * NBLK_G + l);
          if (__all((int)(f >= tgt))) break;
          __builtin_amdgcn_s_sleep(1);
        }
      }
      __syncthreads();
    }

    // ---- coherent fragment loads: h(t-1), this wave's k-slice ----
    const uint32_t* hrow =
        hsp + ((size_t)(rpar * NGRP + grp) * GB + (l & 15)) * NH;
    uint4 q[KTW][2];
#pragma unroll
    for (int kt = 0; kt < KTW; ++kt) {
      const uint32_t* p = hrow + kbase + kt * 32;
      q[kt][0] = ld_b128_coh(p);
      q[kt][1] = ld_b128_coh(p + 4);
    }
    asm volatile("s_waitcnt vmcnt(0)" ::: "memory");
    __builtin_amdgcn_sched_barrier(0);

    bf16x8 bh[KTW], bl[KTW];
#pragma unroll
    for (int kt = 0; kt < KTW; ++kt) {
      union { uint32_t u[4]; bf16x8 v; } H, L;
      H.u[0] = __builtin_amdgcn_perm(q[kt][0].y, q[kt][0].x, SEL_HI);
      L.u[0] = __builtin_amdgcn_perm(q[kt][0].y, q[kt][0].x, SEL_LO);
      H.u[1] = __builtin_amdgcn_perm(q[kt][0].w, q[kt][0].z, SEL_HI);
      L.u[1] = __builtin_amdgcn_perm(q[kt][0].w, q[kt][0].z, SEL_LO);
      H.u[2] = __builtin_amdgcn_perm(q[kt][1].y, q[kt][1].x, SEL_HI);
      L.u[2] = __builtin_amdgcn_perm(q[kt][1].y, q[kt][1].x, SEL_LO);
      H.u[3] = __builtin_amdgcn_perm(q[kt][1].w, q[kt][1].z, SEL_HI);
      L.u[3] = __builtin_amdgcn_perm(q[kt][1].w, q[kt][1].z, SEL_LO);
      bh[kt] = H.v; bl[kt] = L.v;
    }

    // ---- MFMA: 3-pass bf16 hi/lo split; w-hi streamed from LDS ----
    f32x4 acc[3];
#pragma unroll
    for (int g = 0; g < 3; ++g) acc[g] = (f32x4){0.f, 0.f, 0.f, 0.f};
#pragma unroll
    for (int kt = 0; kt < KTW; ++kt) {
#pragma unroll
      for (int g = 0; g < 3; ++g) {
        const bf16x8 whi =
            *(const bf16x8*)&wHs[(((g * WAVES + wv) * KTW + kt) * 64 + l) * 4];
        acc[g] = __builtin_amdgcn_mfma_f32_16x16x32_bf16(whi, bh[kt], acc[g], 0, 0, 0);
        acc[g] = __builtin_amdgcn_mfma_f32_16x16x32_bf16(whi, bl[kt], acc[g], 0, 0, 0);
        acc[g] = __builtin_amdgcn_mfma_f32_16x16x32_bf16(wlo[g][kt], bh[kt], acc[g], 0, 0, 0);
      }
    }

#pragma unroll
    for (int g = 0; g < 3; ++g)
#pragma unroll
      for (int qi = 0; qi < 4; ++qi)
        part[wv][g][(l >> 4) * 4 + qi][l & 15] = acc[g][qi];
    __syncthreads();   // barrier1: partials ready; orders h-reads before gating

    if (tid < 256) {
      float ghr = 0.f, ghz = 0.f, ghn = 0.f;
#pragma unroll
      for (int ww = 0; ww < WAVES; ++ww) {
        ghr += part[ww][0][jl][b];
        ghz += part[ww][1][jl][b];
        ghn += part[ww][2][jl][b];
      }
      const float r = 1.f / (1.f + expf(-(xr + ghr + bhr)));
      const float z = 1.f / (1.f + expf(-(xz + ghz + bhz)));
      const float n = tanhf(xn + r * (ghn + bhn));
      const float h = (1.f - z) * n + z * hprev;
      hprev = h;

      union { __bf16 f; uint16_t u; } hh, hl;
      hh.f = (__bf16)h;
      hl.f = (__bf16)(h - (float)hh.f);
      // step-exchange store (critical path), then drain ONLY this wave
      st_b32_coh(hsp + ((size_t)(wpar * NGRP + grp) * GB + b) * NH + j,
                 ((uint32_t)hh.u << 16) | hl.u);
      asm volatile("s_waitcnt vmcnt(0)" ::: "memory");
      // layer-handoff planes: fly un-acked (read only cross-kernel)
      const size_t po = ((size_t)t * BATCH + n0 + b) * NH + j;
      ahi[po] = hh.f;
      alo[po] = hl.f;
    }

    // barrier2: LDS-only drain (act stores keep flying)
    asm volatile("s_waitcnt lgkmcnt(0)" ::: "memory");
    __builtin_amdgcn_s_barrier();
    __builtin_amdgcn_sched_barrier(0);

    // publish (wave 4 lane 0): all gating waves drained hsp before barrier2,
    // so the flag certifies h(t) visible at IC. Wave 4 never polls, so its
    // un-drained flag store never delays a poll.
    if (tid == 256) st_b32_coh(flg + grp * NBLK_G + blk_in, (uint32_t)(i + 1));
  }
}

// ---------------------------------------------------------------------------
__global__ __launch_bounds__(256) void k_proj(
    const __bf16* __restrict__ ahi, const __bf16* __restrict__ alo,
    const float* __restrict__ wp, const float* __restrict__ bp,
    float* __restrict__ out) {
  int b = blockIdx.x;
  int f = threadIdx.x;
  __shared__ float hs[NH];
  __shared__ float red[FCD];

  const size_t base = ((size_t)(T_FRAMES - 1) * BATCH + b) * NH;
  for (int k = f; k < NH; k += FCD)
    hs[k] = (float)ahi[base + k] + (float)alo[base + k];
  __syncthreads();

  float acc = bp[f];
  const float* wrow = wp + (size_t)f * NH;
#pragma unroll 4
  for (int k = 0; k < NH; k += 4) {
    const float4 w4 = *(const float4*)&wrow[k];
    acc = fmaf(w4.x, hs[k], acc);
    acc = fmaf(w4.y, hs[k + 1], acc);
    acc = fmaf(w4.z, hs[k + 2], acc);
    acc = fmaf(w4.w, hs[k + 3], acc);
  }
  red[f] = acc * acc;
  __syncthreads();
  for (int s = FCD / 2; s > 0; s >>= 1) {
    if (f < s) red[f] += red[f + s];
    __syncthreads();
  }
  float nrm = sqrtf(red[0]);
  out[(size_t)b * FCD + f] = acc / fmaxf(nrm, 1e-12f);
}

// ---------------------------------------------------------------------------
extern "C" void kernel_launch(void* const* d_in, const int* in_sizes, int n_in,
                              void* d_out, int out_size, void* d_ws, size_t ws_size,
                              hipStream_t stream) {
  const float* x        = (const float*)d_in[0];
  const float* wih0     = (const float*)d_in[1];
  const float* whh0     = (const float*)d_in[2];
  const float* bih0     = (const float*)d_in[3];
  const float* bhh0     = (const float*)d_in[4];
  const float* wih_rest = (const float*)d_in[5];
  const float* whh_rest = (const float*)d_in[6];
  const float* bih_rest = (const float*)d_in[7];
  const float* bhh_rest = (const float*)d_in[8];
  const float* wp       = (const float*)d_in[9];
  const float* bp       = (const float*)d_in[10];
  float* out = (float*)d_out;

  // ---- workspace layout (bytes) ----
  const size_t ahi_b = (size_t)T_FRAMES * BATCH * NH * 2;    // 33,554,432
  const size_t whl_b = (size_t)2 * NG * NH * 2;              // 12,582,912/plane
  const size_t xT_b  = (size_t)T_FRAMES * NMELS * BATCH * 4; //  5,242,880
  const size_t hsp_b = (size_t)2 * NGRP * GB * NH * 4;       //    524,288
  const size_t flg_b = 4096;
  const size_t fixed = 2 * ahi_b + 2 * whl_b + xT_b + hsp_b + flg_b;

  char* wsb = (char*)d_ws;
  __bf16*    ahi  = (__bf16*)wsb;
  __bf16*    alo  = (__bf16*)(wsb + ahi_b);
  __bf16*    wchi = (__bf16*)(wsb + 2 * ahi_b);              // [2][NG][NH]
  __bf16*    wclo = (__bf16*)(wsb + 2 * ahi_b + whl_b);
  float*     xT   = (float*)(wsb + 2 * ahi_b + 2 * whl_b);
  uint32_t*  hsp  = (uint32_t*)(wsb + 2 * ahi_b + 2 * whl_b + xT_b);
  uint32_t*  flg  = (uint32_t*)(wsb + 2 * ahi_b + 2 * whl_b + xT_b + hsp_b);
  float*     xp   = (float*)(wsb + fixed);

  int Tc = 0;
  for (int c = T_FRAMES; c >= 2; c >>= 1) {
    if (fixed + (size_t)c * NG * BATCH * 4 <= ws_size) { Tc = c; break; }
  }
  if (Tc == 0) return;

  k_transpose_x<<<T_FRAMES, 256, 0, stream>>>(x, xT);
  k_wconv<<<(NG * NH) / 1024, 256, 0, stream>>>(wih_rest, wchi, wclo);
  k_wconv<<<(NG * NH) / 1024, 256, 0, stream>>>(
      wih_rest + (size_t)NG * NH, wchi + (size_t)NG * NH, wclo + (size_t)NG * NH);

  for (int layer = 0; layer < 3; ++layer) {
    const float* whh; const float* bih; const float* bhh;
    if (layer == 0) {
      whh = whh0; bih = bih0; bhh = bhh0;
    } else {
      whh = whh_rest + (size_t)(layer - 1) * NG * NH;
      bih = bih_rest + (size_t)(layer - 1) * NG;
      bhh = bhh_rest + (size_t)(layer - 1) * NG;
    }
    hipMemsetAsync(hsp, 0, hsp_b, stream);   // h(-1) = 0 (both parities)
    for (int c0 = 0; c0 < T_FRAMES; c0 += Tc) {
      if (layer == 0) {
        dim3 gg(NG / 64, Tc);
        k_gemm_xp<<<gg, 256, 0, stream>>>(xT, wih0, bih, xp, NMELS, c0);
      } else {
        const __bf16* whi_l = wchi + (size_t)(layer - 1) * NG * NH;
        const __bf16* wlo_l = wclo + (size_t)(layer - 1) * NG * NH;
        dim3 gg2(NG / 128, (Tc * BATCH) / 128);
        k_gemm_mfma2<<<gg2, 256, 0, stream>>>(
            whi_l, wlo_l,
            ahi + (size_t)c0 * BATCH * NH, alo + (size_t)c0 * BATCH * NH,
            bih, xp);
      }
      hipMemsetAsync(flg, 0, NGRP * NBLK_G * sizeof(uint32_t), stream);
      k_gru_layer<<<NBLK, 512, 0, stream>>>(xp, whh, bhh, ahi, alo,
                                            hsp, flg, c0, c0 + Tc);
    }
  }

  k_proj<<<BATCH, FCD, 0, stream>>>(ahi, alo, wp, bp, out);
}

// Round 14
// 4449.363 us; speedup vs baseline: 1.4420x; 1.4420x over previous
//
#include <hip/hip_runtime.h>
#include <math.h>
#include <stdint.h>

#define T_FRAMES 256
#define BATCH    64
#define NH       1024
#define NG       3072   // 3*NH
#define NMELS    80
#define FCD      256

// ---- persistent GRU geometry ----
#define NGRP   4                  // batch groups
#define GB     16                 // batches per group (MFMA N)
#define JBLK   16                 // j's per block (MFMA M)
#define NBLK_G 64                 // blocks per group = NH/JBLK
#define NBLK   (NGRP * NBLK_G)    // 256 blocks = 1/CU
#define WAVES  8
#define KSL    (NH / WAVES)       // 128 k per wave
#define KTW    (KSL / 32)         // 4 ktiles per wave

typedef __bf16 bf16x8 __attribute__((ext_vector_type(8)));
typedef __bf16 bf16x4 __attribute__((ext_vector_type(4)));
typedef float  f32x4  __attribute__((ext_vector_type(4)));

// IC-coherent access (sc0 sc1): bypass L1/L2, serialize at Infinity Cache.
__device__ __forceinline__ uint4 ld_b128_coh(const uint32_t* p) {
  uint4 r;
  asm volatile("global_load_dwordx4 %0, %1, off sc0 sc1"
               : "=v"(r) : "v"(p) : "memory");
  return r;
}
__device__ __forceinline__ uint32_t ld_b32_coh(const uint32_t* p) {
  uint32_t r;
  asm volatile("global_load_dword %0, %1, off sc0 sc1\n\ts_waitcnt vmcnt(0)"
               : "=v"(r) : "v"(p) : "memory");
  return r;
}
__device__ __forceinline__ void st_b32_coh(uint32_t* p, uint32_t v) {
  asm volatile("global_store_dword %0, %1, off sc0 sc1"
               :: "v"(p), "v"(v) : "memory");
}

// global -> LDS direct copy, 16B per lane
__device__ __forceinline__ void gload16(const void* g, void* l) {
  __builtin_amdgcn_global_load_lds(
      (const __attribute__((address_space(1))) void*)g,
      (__attribute__((address_space(3))) void*)l, 16, 0, 0);
}

// ---------------------------------------------------------------------------
__global__ __launch_bounds__(256) void k_transpose_x(
    const float* __restrict__ x, float* __restrict__ xT) {
  int t = blockIdx.x;
  __shared__ float tile[BATCH][NMELS + 1];
  for (int idx = threadIdx.x; idx < BATCH * NMELS; idx += 256) {
    int b = idx / NMELS, i = idx % NMELS;
    tile[b][i] = x[((size_t)b * T_FRAMES + t) * NMELS + i];
  }
  __syncthreads();
  for (int idx = threadIdx.x; idx < BATCH * NMELS; idx += 256) {
    int i = idx / BATCH, b = idx % BATCH;
    xT[((size_t)t * NMELS + i) * BATCH + b] = tile[b][i];
  }
}

// ---------------------------------------------------------------------------
__global__ __launch_bounds__(256) void k_wconv(
    const float* __restrict__ W, __bf16* __restrict__ hi,
    __bf16* __restrict__ lo) {
  size_t i = ((size_t)blockIdx.x * 256 + threadIdx.x) * 4;
  float4 w = *(const float4*)&W[i];
  float f[4] = {w.x, w.y, w.z, w.w};
  bf16x4 H, L;
#pragma unroll
  for (int e = 0; e < 4; ++e) {
    __bf16 hv = (__bf16)f[e];
    H[e] = hv;
    L[e] = (__bf16)(f[e] - (float)hv);
  }
  *(bf16x4*)&hi[i] = H;
  *(bf16x4*)&lo[i] = L;
}

// ---------------------------------------------------------------------------
// fp32 xp GEMM (layer 0 only, K=NMELS)
__global__ __launch_bounds__(256) void k_gemm_xp(
    const float* __restrict__ A, const float* __restrict__ W,
    const float* __restrict__ bias, float* __restrict__ xp, int K, int t0) {
  int ty = blockIdx.y;
  int t  = t0 + ty;
  int g0 = blockIdx.x * 64;
  __shared__ float As[16][64];
  __shared__ float Bs[16][64];

  int tid = threadIdx.x;
  int b0 = (tid & 15) * 4;
  int gq = tid >> 4;
  int ar = tid >> 4;
  int ac = (tid & 15) * 4;
  int bg = tid & 63;
  int bk = (tid >> 6) * 4;

  float acc[4][4] = {{0.f}};
  const float* At = A + (size_t)t * K * BATCH;

  for (int k0 = 0; k0 < K; k0 += 16) {
    *(float4*)&As[ar][ac] = *(const float4*)&At[(size_t)(k0 + ar) * BATCH + ac];
    float4 w = *(const float4*)&W[(size_t)(g0 + bg) * K + k0 + bk];
    Bs[bk + 0][bg] = w.x; Bs[bk + 1][bg] = w.y;
    Bs[bk + 2][bg] = w.z; Bs[bk + 3][bg] = w.w;
    __syncthreads();
#pragma unroll
    for (int kt = 0; kt < 16; ++kt) {
      const float4 a  = *(const float4*)&As[kt][b0];
      const float4 g4 = *(const float4*)&Bs[kt][gq * 4];
      const float av[4] = {a.x, a.y, a.z, a.w};
      const float gv[4] = {g4.x, g4.y, g4.z, g4.w};
#pragma unroll
      for (int gi = 0; gi < 4; ++gi)
#pragma unroll
        for (int bj = 0; bj < 4; ++bj)
          acc[gi][bj] = fmaf(gv[gi], av[bj], acc[gi][bj]);
    }
    __syncthreads();
  }
#pragma unroll
  for (int gi = 0; gi < 4; ++gi) {
    int g = g0 + gq * 4 + gi;
    float bv = bias[g];
    float4 o = make_float4(acc[gi][0] + bv, acc[gi][1] + bv,
                           acc[gi][2] + bv, acc[gi][3] + bv);
    *(float4*)&xp[((size_t)ty * NG + g) * BATCH + b0] = o;
  }
}

// ---------------------------------------------------------------------------
// Tiled MFMA xp GEMM (layers 1,2) — unchanged (verified rounds 9-13).
__global__ __launch_bounds__(256, 2) void k_gemm_mfma2(
    const __bf16* __restrict__ Whi, const __bf16* __restrict__ Wlo,
    const __bf16* __restrict__ Ahi, const __bf16* __restrict__ Alo,
    const float* __restrict__ bias, float* __restrict__ xp) {
  __shared__ __bf16 lds[4][128][64];   // 64 KB
  const int tid = threadIdx.x;
  const int l   = tid & 63;
  const int wv  = tid >> 6;

  int flat  = blockIdx.y * gridDim.x + blockIdx.x;
  int total = gridDim.x * gridDim.y;
  if ((total & 7) == 0) flat = (flat & 7) * (total >> 3) + (flat >> 3);
  const int m0 = (flat % gridDim.x) * 128;
  const int n0 = (flat / gridDim.x) * 128;

  const int wm = (wv & 1) * 64;
  const int wn = (wv >> 1) * 64;

  const int srow = l >> 3;
  const int xcol = ((l & 7) ^ srow) * 8;
  const __bf16* sbase;
  if      (wv == 0) sbase = Whi + (size_t)m0 * NH;
  else if (wv == 1) sbase = Wlo + (size_t)m0 * NH;
  else if (wv == 2) sbase = Ahi + (size_t)n0 * NH;
  else              sbase = Alo + (size_t)n0 * NH;
  const __bf16* ssrc = sbase + (size_t)srow * NH + xcol;

  f32x4 acc[4][4];
#pragma unroll
  for (int mf = 0; mf < 4; ++mf)
#pragma unroll
    for (int nf = 0; nf < 4; ++nf) acc[mf][nf] = (f32x4){0.f, 0.f, 0.f, 0.f};

  for (int k0 = 0; k0 < NH; k0 += 64) {
#pragma unroll
    for (int c = 0; c < 16; ++c)
      gload16(ssrc + (size_t)(c * 8) * NH + k0, &lds[wv][c * 8][0]);
    __syncthreads();

#pragma unroll
    for (int ksub = 0; ksub < 2; ++ksub) {
      const int colr = (((l >> 4) + ksub * 4) ^ (l & 7)) * 8;
      bf16x8 wfh[4], wfl[4], afh[4], afl[4];
#pragma unroll
      for (int mf = 0; mf < 4; ++mf) {
        const int row = wm + mf * 16 + (l & 15);
        wfh[mf] = *(const bf16x8*)&lds[0][row][colr];
        wfl[mf] = *(const bf16x8*)&lds[1][row][colr];
      }
#pragma unroll
      for (int nf = 0; nf < 4; ++nf) {
        const int row = wn + nf * 16 + (l & 15);
        afh[nf] = *(const bf16x8*)&lds[2][row][colr];
        afl[nf] = *(const bf16x8*)&lds[3][row][colr];
      }
#pragma unroll
      for (int mf = 0; mf < 4; ++mf)
#pragma unroll
        for (int nf = 0; nf < 4; ++nf) {
          acc[mf][nf] = __builtin_amdgcn_mfma_f32_16x16x32_bf16(wfh[mf], afh[nf], acc[mf][nf], 0, 0, 0);
          acc[mf][nf] = __builtin_amdgcn_mfma_f32_16x16x32_bf16(wfh[mf], afl[nf], acc[mf][nf], 0, 0, 0);
          acc[mf][nf] = __builtin_amdgcn_mfma_f32_16x16x32_bf16(wfl[mf], afh[nf], acc[mf][nf], 0, 0, 0);
        }
    }
    __syncthreads();
  }

  const int cr = l >> 4;
  const int cc = l & 15;
#pragma unroll
  for (int mf = 0; mf < 4; ++mf) {
#pragma unroll
    for (int q = 0; q < 4; ++q) {
      const int g = m0 + wm + mf * 16 + cr * 4 + q;
      const float bv = bias[g];
#pragma unroll
      for (int nf = 0; nf < 4; ++nf) {
        const int n = n0 + wn + nf * 16 + cc;
        xp[((size_t)(n >> 6) * NG + g) * BATCH + (n & 63)] =
            acc[mf][nf][q] + bv;
      }
    }
  }
}

// ---------------------------------------------------------------------------
// Persistent MFMA GRU layer — exact r9 protocol (595us measured) with ONE
// change: act-plane stores delegated to waves 4-7 via a 1KB LDS handoff, so
// gating waves drain only their hsp store (vmcnt is IN-ORDER per wave: any
// un-acked store is paid at the wave's next vmcnt(0) — r12/r13 lesson).
// Per step t: wave0 polls 64 flags >= fbase+t; __syncthreads; h loads (IC,
// vmcnt0); MFMA; barrier1; gating: hsp store + per-wave vmcnt(0) + hx
// ds_write; lgkm-barrier2; tid0 publishes fbase+t+1; waves 4-7 read hx and
// issue act stores (un-acked; drain overlaps next poll window).
__global__ __launch_bounds__(512, 1) void k_gru_layer(
    const float* __restrict__ xp,     // [Tc][NG][BATCH], frame t0 first
    const float* __restrict__ whh,    // [NG][NH]
    const float* __restrict__ bhh,    // [NG]
    __bf16* __restrict__ ahi,         // [T][BATCH][NH] h hi plane
    __bf16* __restrict__ alo,         // [T][BATCH][NH] h lo plane
    uint32_t* __restrict__ hsp,       // [2][NGRP][GB][NH] packed u32
    uint32_t* __restrict__ flg,       // [NGRP][64] monotonic flags
    int t0, int tEnd, int fbase) {
  const int tid = threadIdx.x;
  const int l   = tid & 63;
  const int wv  = tid >> 6;
  const int grp    = (blockIdx.x & 7) >> 1;
  const int blk_in = (blockIdx.x >> 3) * 2 + (blockIdx.x & 1);
  const int j0 = blk_in * JBLK;
  const int n0 = grp * GB;

  __shared__ uint32_t wHs[3 * WAVES * KTW * 64 * 4];   // 96 KB hi fragments
  __shared__ float part[WAVES][3][JBLK][GB];           // r9 layout (24 KB)
  __shared__ uint32_t hx[JBLK * GB];                   // 1 KB packed-h handoff

  // ---- stage weights: hi -> LDS fragment slots, lo -> VGPRs ----
  const int row_j = j0 + (l & 15);
  const int kbase = wv * KSL + (l >> 4) * 8;
  bf16x8 wlo[3][KTW];
#pragma unroll
  for (int g = 0; g < 3; ++g) {
#pragma unroll
    for (int kt = 0; kt < KTW; ++kt) {
      const float* wp8 = whh + (size_t)(g * NH + row_j) * NH + kbase + kt * 32;
      float4 w0 = *(const float4*)wp8;
      float4 w1 = *(const float4*)(wp8 + 4);
      float f[8] = {w0.x, w0.y, w0.z, w0.w, w1.x, w1.y, w1.z, w1.w};
      bf16x8 hi, lo;
#pragma unroll
      for (int e = 0; e < 8; ++e) {
        __bf16 hv = (__bf16)f[e];
        hi[e] = hv;
        lo[e] = (__bf16)(f[e] - (float)hv);
      }
      *(bf16x8*)&wHs[(((g * WAVES + wv) * KTW + kt) * 64 + l) * 4] = hi;
      wlo[g][kt] = lo;
    }
  }

  const int jl = tid >> 4;
  const int b  = tid & 15;
  const int j  = j0 + (jl & 15);
  float hprev = 0.f, bhr = 0.f, bhz = 0.f, bhn = 0.f;
  if (tid < 256) {
    if (t0 > 0) {
      const size_t po = ((size_t)(t0 - 1) * BATCH + n0 + b) * NH + j;
      hprev = (float)ahi[po] + (float)alo[po];
    }
    bhr = bhh[j]; bhz = bhh[NH + j]; bhn = bhh[2 * NH + j];
  }
  __syncthreads();

  const uint32_t SEL_HI = 0x07060302u;
  const uint32_t SEL_LO = 0x05040100u;

  for (int t = t0; t < tEnd; ++t) {
    const int rpar = (t + 1) & 1;   // parity holding h(t-1)
    const int wpar = t & 1;         // parity receiving h(t)

    // early xp loads (plain, L2/HBM) — overlap with poll + h loads
    float xr = 0.f, xz = 0.f, xn = 0.f;
    if (tid < 256) {
      const float* xpt = xp + (size_t)(t - t0) * NG * BATCH;
      xr = xpt[(size_t)(0 * NH + j) * BATCH + n0 + b];
      xz = xpt[(size_t)(1 * NH + j) * BATCH + n0 + b];
      xn = xpt[(size_t)(2 * NH + j) * BATCH + n0 + b];
    }

    // ---- wait for all producers of h(t-1): poll 64 flags (wave 0) ----
    if (t > t0) {
      if (wv == 0) {
        const uint32_t tgt = (uint32_t)(fbase + t);
        while (true) {
          uint32_t f = ld_b32_coh(flg + grp * NBLK_G + l);
          if (__all((int)(f >= tgt))) break;
          __builtin_amdgcn_s_sleep(1);
        }
      }
      __syncthreads();
    }

    // ---- coherent fragment loads: h(t-1), this wave's k-slice ----
    const uint32_t* hrow =
        hsp + ((size_t)(rpar * NGRP + grp) * GB + (l & 15)) * NH;
    uint4 q[KTW][2];
#pragma unroll
    for (int kt = 0; kt < KTW; ++kt) {
      const uint32_t* p = hrow + kbase + kt * 32;
      q[kt][0] = ld_b128_coh(p);
      q[kt][1] = ld_b128_coh(p + 4);
    }
    asm volatile("s_waitcnt vmcnt(0)" ::: "memory");
    __builtin_amdgcn_sched_barrier(0);

    bf16x8 bh[KTW], bl[KTW];
#pragma unroll
    for (int kt = 0; kt < KTW; ++kt) {
      union { uint32_t u[4]; bf16x8 v; } H, L;
      H.u[0] = __builtin_amdgcn_perm(q[kt][0].y, q[kt][0].x, SEL_HI);
      L.u[0] = __builtin_amdgcn_perm(q[kt][0].y, q[kt][0].x, SEL_LO);
      H.u[1] = __builtin_amdgcn_perm(q[kt][0].w, q[kt][0].z, SEL_HI);
      L.u[1] = __builtin_amdgcn_perm(q[kt][0].w, q[kt][0].z, SEL_LO);
      H.u[2] = __builtin_amdgcn_perm(q[kt][1].y, q[kt][1].x, SEL_HI);
      L.u[2] = __builtin_amdgcn_perm(q[kt][1].y, q[kt][1].x, SEL_LO);
      H.u[3] = __builtin_amdgcn_perm(q[kt][1].w, q[kt][1].z, SEL_HI);
      L.u[3] = __builtin_amdgcn_perm(q[kt][1].w, q[kt][1].z, SEL_LO);
      bh[kt] = H.v; bl[kt] = L.v;
    }

    // ---- MFMA: 3-pass bf16 hi/lo split; w-hi streamed from LDS ----
    f32x4 acc[3];
#pragma unroll
    for (int g = 0; g < 3; ++g) acc[g] = (f32x4){0.f, 0.f, 0.f, 0.f};
#pragma unroll
    for (int kt = 0; kt < KTW; ++kt) {
#pragma unroll
      for (int g = 0; g < 3; ++g) {
        const bf16x8 whi =
            *(const bf16x8*)&wHs[(((g * WAVES + wv) * KTW + kt) * 64 + l) * 4];
        acc[g] = __builtin_amdgcn_mfma_f32_16x16x32_bf16(whi, bh[kt], acc[g], 0, 0, 0);
        acc[g] = __builtin_amdgcn_mfma_f32_16x16x32_bf16(whi, bl[kt], acc[g], 0, 0, 0);
        acc[g] = __builtin_amdgcn_mfma_f32_16x16x32_bf16(wlo[g][kt], bh[kt], acc[g], 0, 0, 0);
      }
    }

#pragma unroll
    for (int g = 0; g < 3; ++g)
#pragma unroll
      for (int qi = 0; qi < 4; ++qi)
        part[wv][g][(l >> 4) * 4 + qi][l & 15] = acc[g][qi];
    __syncthreads();   // barrier1: partials ready; orders h-reads before gating

    if (tid < 256) {
      float ghr = 0.f, ghz = 0.f, ghn = 0.f;
#pragma unroll
      for (int ww = 0; ww < WAVES; ++ww) {
        ghr += part[ww][0][jl][b];
        ghz += part[ww][1][jl][b];
        ghn += part[ww][2][jl][b];
      }
      const float r = 1.f / (1.f + expf(-(xr + ghr + bhr)));
      const float z = 1.f / (1.f + expf(-(xz + ghz + bhz)));
      const float n = tanhf(xn + r * (ghn + bhn));
      const float h = (1.f - z) * n + z * hprev;
      hprev = h;

      union { __bf16 f; uint16_t u; } hh, hl;
      hh.f = (__bf16)h;
      hl.f = (__bf16)(h - (float)hh.f);
      const uint32_t pk = ((uint32_t)hh.u << 16) | hl.u;
      // step-exchange store (critical path); queue holds ONLY this store
      st_b32_coh(hsp + ((size_t)(wpar * NGRP + grp) * GB + b) * NH + j,
                 pk);
      asm volatile("s_waitcnt vmcnt(0)" ::: "memory");
      hx[jl * GB + b] = pk;            // handoff for act-plane writers
    }

    // barrier2: LDS-only drain (hsp already drained per-wave above)
    asm volatile("s_waitcnt lgkmcnt(0)" ::: "memory");
    __builtin_amdgcn_s_barrier();
    __builtin_amdgcn_sched_barrier(0);

    // publish: every gating wave drained its hsp store before barrier2, so
    // the flag certifies h(t) visible at IC. No act-store wait on this path.
    if (tid == 0) st_b32_coh(flg + grp * NBLK_G + blk_in,
                             (uint32_t)(fbase + t + 1));

    // act-plane stores by waves 4-7 (un-acked; drain overlaps next poll)
    if (wv >= 4) {
      const int idx = tid - 256;            // 0..255
      const uint32_t pk = hx[idx];
      const int jj = j0 + (idx >> 4);
      const int bb = idx & 15;
      union { uint16_t u; __bf16 f; } H2, L2;
      H2.u = (uint16_t)(pk >> 16);
      L2.u = (uint16_t)(pk & 0xffffu);
      const size_t po = ((size_t)t * BATCH + n0 + bb) * NH + jj;
      ahi[po] = H2.f;
      alo[po] = L2.f;
    }
  }
}

// ---------------------------------------------------------------------------
__global__ __launch_bounds__(256) void k_proj(
    const __bf16* __restrict__ ahi, const __bf16* __restrict__ alo,
    const float* __restrict__ wp, const float* __restrict__ bp,
    float* __restrict__ out) {
  int b = blockIdx.x;
  int f = threadIdx.x;
  __shared__ float hs[NH];
  __shared__ float red[FCD];

  const size_t base = ((size_t)(T_FRAMES - 1) * BATCH + b) * NH;
  for (int k = f; k < NH; k += FCD)
    hs[k] = (float)ahi[base + k] + (float)alo[base + k];
  __syncthreads();

  float acc = bp[f];
  const float* wrow = wp + (size_t)f * NH;
#pragma unroll 4
  for (int k = 0; k < NH; k += 4) {
    const float4 w4 = *(const float4*)&wrow[k];
    acc = fmaf(w4.x, hs[k], acc);
    acc = fmaf(w4.y, hs[k + 1], acc);
    acc = fmaf(w4.z, hs[k + 2], acc);
    acc = fmaf(w4.w, hs[k + 3], acc);
  }
  red[f] = acc * acc;
  __syncthreads();
  for (int s = FCD / 2; s > 0; s >>= 1) {
    if (f < s) red[f] += red[f + s];
    __syncthreads();
  }
  float nrm = sqrtf(red[0]);
  out[(size_t)b * FCD + f] = acc / fmaxf(nrm, 1e-12f);
}

// ---------------------------------------------------------------------------
extern "C" void kernel_launch(void* const* d_in, const int* in_sizes, int n_in,
                              void* d_out, int out_size, void* d_ws, size_t ws_size,
                              hipStream_t stream) {
  const float* x        = (const float*)d_in[0];
  const float* wih0     = (const float*)d_in[1];
  const float* whh0     = (const float*)d_in[2];
  const float* bih0     = (const float*)d_in[3];
  const float* bhh0     = (const float*)d_in[4];
  const float* wih_rest = (const float*)d_in[5];
  const float* whh_rest = (const float*)d_in[6];
  const float* bih_rest = (const float*)d_in[7];
  const float* bhh_rest = (const float*)d_in[8];
  const float* wp       = (const float*)d_in[9];
  const float* bp       = (const float*)d_in[10];
  float* out = (float*)d_out;

  // ---- workspace layout (bytes) ----
  const size_t ahi_b = (size_t)T_FRAMES * BATCH * NH * 2;    // 33,554,432
  const size_t whl_b = (size_t)2 * NG * NH * 2;              // 12,582,912/plane
  const size_t xT_b  = (size_t)T_FRAMES * NMELS * BATCH * 4; //  5,242,880
  const size_t hsp_b = (size_t)2 * NGRP * GB * NH * 4;       //    524,288
  const size_t flg_b = 4096;
  const size_t fixed = 2 * ahi_b + 2 * whl_b + xT_b + hsp_b + flg_b;

  char* wsb = (char*)d_ws;
  __bf16*    ahi  = (__bf16*)wsb;
  __bf16*    alo  = (__bf16*)(wsb + ahi_b);
  __bf16*    wchi = (__bf16*)(wsb + 2 * ahi_b);              // [2][NG][NH]
  __bf16*    wclo = (__bf16*)(wsb + 2 * ahi_b + whl_b);
  float*     xT   = (float*)(wsb + 2 * ahi_b + 2 * whl_b);
  uint32_t*  hsp  = (uint32_t*)(wsb + 2 * ahi_b + 2 * whl_b + xT_b);
  uint32_t*  flg  = (uint32_t*)(wsb + 2 * ahi_b + 2 * whl_b + xT_b + hsp_b);
  float*     xp   = (float*)(wsb + fixed);

  int Tc = 0;
  for (int c = T_FRAMES; c >= 2; c >>= 1) {
    if (fixed + (size_t)c * NG * BATCH * 4 <= ws_size) { Tc = c; break; }
  }
  if (Tc == 0) return;

  k_transpose_x<<<T_FRAMES, 256, 0, stream>>>(x, xT);
  k_wconv<<<(NG * NH) / 1024, 256, 0, stream>>>(wih_rest, wchi, wclo);
  k_wconv<<<(NG * NH) / 1024, 256, 0, stream>>>(
      wih_rest + (size_t)NG * NH, wchi + (size_t)NG * NH, wclo + (size_t)NG * NH);
  hipMemsetAsync(flg, 0, flg_b, stream);   // flags monotonic per launch

  for (int layer = 0; layer < 3; ++layer) {
    const float* whh; const float* bih; const float* bhh;
    if (layer == 0) {
      whh = whh0; bih = bih0; bhh = bhh0;
    } else {
      whh = whh_rest + (size_t)(layer - 1) * NG * NH;
      bih = bih_rest + (size_t)(layer - 1) * NG;
      bhh = bhh_rest + (size_t)(layer - 1) * NG;
    }
    hipMemsetAsync(hsp, 0, hsp_b, stream);   // h(-1) = 0 (both parities)
    const int fbase = layer * T_FRAMES;
    for (int c0 = 0; c0 < T_FRAMES; c0 += Tc) {
      if (layer == 0) {
        dim3 gg(NG / 64, Tc);
        k_gemm_xp<<<gg, 256, 0, stream>>>(xT, wih0, bih, xp, NMELS, c0);
      } else {
        const __bf16* whi_l = wchi + (size_t)(layer - 1) * NG * NH;
        const __bf16* wlo_l = wclo + (size_t)(layer - 1) * NG * NH;
        dim3 gg2(NG / 128, (Tc * BATCH) / 128);
        k_gemm_mfma2<<<gg2, 256, 0, stream>>>(
            whi_l, wlo_l,
            ahi + (size_t)c0 * BATCH * NH, alo + (size_t)c0 * BATCH * NH,
            bih, xp);
      }
      k_gru_layer<<<NBLK, 512, 0, stream>>>(xp, whh, bhh, ahi, alo,
                                            hsp, flg, c0, c0 + Tc, fbase);
    }
  }

  k_proj<<<BATCH, FCD, 0, stream>>>(ahi, alo, wp, bp, out);
}

// Round 15
// 4203.001 us; speedup vs baseline: 1.5266x; 1.0586x over previous
//
#include <hip/hip_runtime.h>
#include <math.h>
#include <stdint.h>

#define T_FRAMES 256
#define BATCH    64
#define NH       1024
#define NG       3072   // 3*NH
#define NMELS    80
#define FCD      256

// ---- persistent GRU geometry ----
#define NGRP   4                  // batch groups
#define GB     16                 // batches per group (MFMA N)
#define JBLK   16                 // j's per block (MFMA M)
#define NBLK_G 64                 // blocks per group = NH/JBLK
#define NBLK   (NGRP * NBLK_G)    // 256 blocks = 1/CU
#define WAVES  8
#define KSL    (NH / WAVES)       // 128 k per wave
#define KTW    (KSL / 32)         // 4 ktiles per wave

typedef __bf16 bf16x8 __attribute__((ext_vector_type(8)));
typedef __bf16 bf16x4 __attribute__((ext_vector_type(4)));
typedef float  f32x4  __attribute__((ext_vector_type(4)));

// IC-coherent access (sc0 sc1): bypass L1/L2, serialize at Infinity Cache.
__device__ __forceinline__ uint4 ld_b128_coh(const uint32_t* p) {
  uint4 r;
  asm volatile("global_load_dwordx4 %0, %1, off sc0 sc1"
               : "=v"(r) : "v"(p) : "memory");
  return r;
}
__device__ __forceinline__ uint32_t ld_b32_coh(const uint32_t* p) {
  uint32_t r;
  asm volatile("global_load_dword %0, %1, off sc0 sc1\n\ts_waitcnt vmcnt(0)"
               : "=v"(r) : "v"(p) : "memory");
  return r;
}
__device__ __forceinline__ void st_b32_coh(uint32_t* p, uint32_t v) {
  asm volatile("global_store_dword %0, %1, off sc0 sc1"
               :: "v"(p), "v"(v) : "memory");
}

// global -> LDS direct copy, 16B per lane
__device__ __forceinline__ void gload16(const void* g, void* l) {
  __builtin_amdgcn_global_load_lds(
      (const __attribute__((address_space(1))) void*)g,
      (__attribute__((address_space(3))) void*)l, 16, 0, 0);
}

// ---------------------------------------------------------------------------
__global__ __launch_bounds__(256) void k_transpose_x(
    const float* __restrict__ x, float* __restrict__ xT) {
  int t = blockIdx.x;
  __shared__ float tile[BATCH][NMELS + 1];
  for (int idx = threadIdx.x; idx < BATCH * NMELS; idx += 256) {
    int b = idx / NMELS, i = idx % NMELS;
    tile[b][i] = x[((size_t)b * T_FRAMES + t) * NMELS + i];
  }
  __syncthreads();
  for (int idx = threadIdx.x; idx < BATCH * NMELS; idx += 256) {
    int i = idx / BATCH, b = idx % BATCH;
    xT[((size_t)t * NMELS + i) * BATCH + b] = tile[b][i];
  }
}

// ---------------------------------------------------------------------------
__global__ __launch_bounds__(256) void k_wconv(
    const float* __restrict__ W, __bf16* __restrict__ hi,
    __bf16* __restrict__ lo) {
  size_t i = ((size_t)blockIdx.x * 256 + threadIdx.x) * 4;
  float4 w = *(const float4*)&W[i];
  float f[4] = {w.x, w.y, w.z, w.w};
  bf16x4 H, L;
#pragma unroll
  for (int e = 0; e < 4; ++e) {
    __bf16 hv = (__bf16)f[e];
    H[e] = hv;
    L[e] = (__bf16)(f[e] - (float)hv);
  }
  *(bf16x4*)&hi[i] = H;
  *(bf16x4*)&lo[i] = L;
}

// ---------------------------------------------------------------------------
// fp32 xp GEMM (layer 0 only, K=NMELS)
__global__ __launch_bounds__(256) void k_gemm_xp(
    const float* __restrict__ A, const float* __restrict__ W,
    const float* __restrict__ bias, float* __restrict__ xp, int K, int t0) {
  int ty = blockIdx.y;
  int t  = t0 + ty;
  int g0 = blockIdx.x * 64;
  __shared__ float As[16][64];
  __shared__ float Bs[16][64];

  int tid = threadIdx.x;
  int b0 = (tid & 15) * 4;
  int gq = tid >> 4;
  int ar = tid >> 4;
  int ac = (tid & 15) * 4;
  int bg = tid & 63;
  int bk = (tid >> 6) * 4;

  float acc[4][4] = {{0.f}};
  const float* At = A + (size_t)t * K * BATCH;

  for (int k0 = 0; k0 < K; k0 += 16) {
    *(float4*)&As[ar][ac] = *(const float4*)&At[(size_t)(k0 + ar) * BATCH + ac];
    float4 w = *(const float4*)&W[(size_t)(g0 + bg) * K + k0 + bk];
    Bs[bk + 0][bg] = w.x; Bs[bk + 1][bg] = w.y;
    Bs[bk + 2][bg] = w.z; Bs[bk + 3][bg] = w.w;
    __syncthreads();
#pragma unroll
    for (int kt = 0; kt < 16; ++kt) {
      const float4 a  = *(const float4*)&As[kt][b0];
      const float4 g4 = *(const float4*)&Bs[kt][gq * 4];
      const float av[4] = {a.x, a.y, a.z, a.w};
      const float gv[4] = {g4.x, g4.y, g4.z, g4.w};
#pragma unroll
      for (int gi = 0; gi < 4; ++gi)
#pragma unroll
        for (int bj = 0; bj < 4; ++bj)
          acc[gi][bj] = fmaf(gv[gi], av[bj], acc[gi][bj]);
    }
    __syncthreads();
  }
#pragma unroll
  for (int gi = 0; gi < 4; ++gi) {
    int g = g0 + gq * 4 + gi;
    float bv = bias[g];
    float4 o = make_float4(acc[gi][0] + bv, acc[gi][1] + bv,
                           acc[gi][2] + bv, acc[gi][3] + bv);
    *(float4*)&xp[((size_t)ty * NG + g) * BATCH + b0] = o;
  }
}

// ---------------------------------------------------------------------------
// Tiled MFMA xp GEMM (layers 1,2) — unchanged (verified rounds 9-14).
__global__ __launch_bounds__(256, 2) void k_gemm_mfma2(
    const __bf16* __restrict__ Whi, const __bf16* __restrict__ Wlo,
    const __bf16* __restrict__ Ahi, const __bf16* __restrict__ Alo,
    const float* __restrict__ bias, float* __restrict__ xp) {
  __shared__ __bf16 lds[4][128][64];   // 64 KB
  const int tid = threadIdx.x;
  const int l   = tid & 63;
  const int wv  = tid >> 6;

  int flat  = blockIdx.y * gridDim.x + blockIdx.x;
  int total = gridDim.x * gridDim.y;
  if ((total & 7) == 0) flat = (flat & 7) * (total >> 3) + (flat >> 3);
  const int m0 = (flat % gridDim.x) * 128;
  const int n0 = (flat / gridDim.x) * 128;

  const int wm = (wv & 1) * 64;
  const int wn = (wv >> 1) * 64;

  const int srow = l >> 3;
  const int xcol = ((l & 7) ^ srow) * 8;
  const __bf16* sbase;
  if      (wv == 0) sbase = Whi + (size_t)m0 * NH;
  else if (wv == 1) sbase = Wlo + (size_t)m0 * NH;
  else if (wv == 2) sbase = Ahi + (size_t)n0 * NH;
  else              sbase = Alo + (size_t)n0 * NH;
  const __bf16* ssrc = sbase + (size_t)srow * NH + xcol;

  f32x4 acc[4][4];
#pragma unroll
  for (int mf = 0; mf < 4; ++mf)
#pragma unroll
    for (int nf = 0; nf < 4; ++nf) acc[mf][nf] = (f32x4){0.f, 0.f, 0.f, 0.f};

  for (int k0 = 0; k0 < NH; k0 += 64) {
#pragma unroll
    for (int c = 0; c < 16; ++c)
      gload16(ssrc + (size_t)(c * 8) * NH + k0, &lds[wv][c * 8][0]);
    __syncthreads();

#pragma unroll
    for (int ksub = 0; ksub < 2; ++ksub) {
      const int colr = (((l >> 4) + ksub * 4) ^ (l & 7)) * 8;
      bf16x8 wfh[4], wfl[4], afh[4], afl[4];
#pragma unroll
      for (int mf = 0; mf < 4; ++mf) {
        const int row = wm + mf * 16 + (l & 15);
        wfh[mf] = *(const bf16x8*)&lds[0][row][colr];
        wfl[mf] = *(const bf16x8*)&lds[1][row][colr];
      }
#pragma unroll
      for (int nf = 0; nf < 4; ++nf) {
        const int row = wn + nf * 16 + (l & 15);
        afh[nf] = *(const bf16x8*)&lds[2][row][colr];
        afl[nf] = *(const bf16x8*)&lds[3][row][colr];
      }
#pragma unroll
      for (int mf = 0; mf < 4; ++mf)
#pragma unroll
        for (int nf = 0; nf < 4; ++nf) {
          acc[mf][nf] = __builtin_amdgcn_mfma_f32_16x16x32_bf16(wfh[mf], afh[nf], acc[mf][nf], 0, 0, 0);
          acc[mf][nf] = __builtin_amdgcn_mfma_f32_16x16x32_bf16(wfh[mf], afl[nf], acc[mf][nf], 0, 0, 0);
          acc[mf][nf] = __builtin_amdgcn_mfma_f32_16x16x32_bf16(wfl[mf], afh[nf], acc[mf][nf], 0, 0, 0);
        }
    }
    __syncthreads();
  }

  const int cr = l >> 4;
  const int cc = l & 15;
#pragma unroll
  for (int mf = 0; mf < 4; ++mf) {
#pragma unroll
    for (int q = 0; q < 4; ++q) {
      const int g = m0 + wm + mf * 16 + cr * 4 + q;
      const float bv = bias[g];
#pragma unroll
      for (int nf = 0; nf < 4; ++nf) {
        const int n = n0 + wn + nf * 16 + cc;
        xp[((size_t)(n >> 6) * NG + g) * BATCH + (n & 63)] =
            acc[mf][nf][q] + bv;
      }
    }
  }
}

// ---------------------------------------------------------------------------
// Persistent MFMA GRU layer — EXACT round-9 protocol (best measured: 595us).
// Per step t: wave0 polls 64 flags >= fbase+t (s_sleep(2)); __syncthreads;
// all waves load h(t-1) frags (IC, vmcnt0); unpack; 3-pass MFMA; part[] in
// r9 layout; barrier1; gating threads (tid<256) reduce + gate + hsp store
// (IC) + act-plane stores; barrier2 (FULL drain: all stores, all waves, in
// parallel inside the barrier wait); tid0 publishes flg = fbase+t+1.
// r10-r14 lesson: vmcnt is a single in-order counter per wave — selective
// draining just moves store latency onto a later vmcnt(0); r9's full-drain
// barrier pays it once, amortized across all waves.
__global__ __launch_bounds__(512, 1) void k_gru_layer(
    const float* __restrict__ xp,     // [Tc][NG][BATCH], frame t0 first
    const float* __restrict__ whh,    // [NG][NH]
    const float* __restrict__ bhh,    // [NG]
    __bf16* __restrict__ ahi,         // [T][BATCH][NH] h hi plane
    __bf16* __restrict__ alo,         // [T][BATCH][NH] h lo plane
    uint32_t* __restrict__ hsp,       // [2][NGRP][GB][NH] packed u32
    uint32_t* __restrict__ flg,       // [NGRP][64] monotonic flags
    int t0, int tEnd, int fbase) {
  const int tid = threadIdx.x;
  const int l   = tid & 63;
  const int wv  = tid >> 6;
  const int grp    = (blockIdx.x & 7) >> 1;
  const int blk_in = (blockIdx.x >> 3) * 2 + (blockIdx.x & 1);
  const int j0 = blk_in * JBLK;
  const int n0 = grp * GB;

  __shared__ uint32_t wHs[3 * WAVES * KTW * 64 * 4];   // 96 KB hi fragments
  __shared__ float part[WAVES][3][JBLK][GB];           // r9 layout (24 KB)

  // ---- stage weights: hi -> LDS fragment slots, lo -> VGPRs ----
  const int row_j = j0 + (l & 15);
  const int kbase = wv * KSL + (l >> 4) * 8;
  bf16x8 wlo[3][KTW];
#pragma unroll
  for (int g = 0; g < 3; ++g) {
#pragma unroll
    for (int kt = 0; kt < KTW; ++kt) {
      const float* wp8 = whh + (size_t)(g * NH + row_j) * NH + kbase + kt * 32;
      float4 w0 = *(const float4*)wp8;
      float4 w1 = *(const float4*)(wp8 + 4);
      float f[8] = {w0.x, w0.y, w0.z, w0.w, w1.x, w1.y, w1.z, w1.w};
      bf16x8 hi, lo;
#pragma unroll
      for (int e = 0; e < 8; ++e) {
        __bf16 hv = (__bf16)f[e];
        hi[e] = hv;
        lo[e] = (__bf16)(f[e] - (float)hv);
      }
      *(bf16x8*)&wHs[(((g * WAVES + wv) * KTW + kt) * 64 + l) * 4] = hi;
      wlo[g][kt] = lo;
    }
  }

  const int jl = tid >> 4;
  const int b  = tid & 15;
  const int j  = j0 + (jl & 15);
  float hprev = 0.f, bhr = 0.f, bhz = 0.f, bhn = 0.f;
  if (tid < 256) {
    if (t0 > 0) {
      const size_t po = ((size_t)(t0 - 1) * BATCH + n0 + b) * NH + j;
      hprev = (float)ahi[po] + (float)alo[po];
    }
    bhr = bhh[j]; bhz = bhh[NH + j]; bhn = bhh[2 * NH + j];
  }
  __syncthreads();

  const uint32_t SEL_HI = 0x07060302u;
  const uint32_t SEL_LO = 0x05040100u;

  for (int t = t0; t < tEnd; ++t) {
    const int rpar = (t + 1) & 1;   // parity holding h(t-1)
    const int wpar = t & 1;         // parity receiving h(t)

    // early xp loads (plain, L2/HBM) — overlap with poll + h loads
    float xr = 0.f, xz = 0.f, xn = 0.f;
    if (tid < 256) {
      const float* xpt = xp + (size_t)(t - t0) * NG * BATCH;
      xr = xpt[(size_t)(0 * NH + j) * BATCH + n0 + b];
      xz = xpt[(size_t)(1 * NH + j) * BATCH + n0 + b];
      xn = xpt[(size_t)(2 * NH + j) * BATCH + n0 + b];
    }

    // ---- wait for all producers of h(t-1): poll 64 flags (wave 0) ----
    if (t > t0) {
      if (wv == 0) {
        const uint32_t tgt = (uint32_t)(fbase + t);
        while (true) {
          uint32_t f = ld_b32_coh(flg + grp * NBLK_G + l);
          if (__all((int)(f >= tgt))) break;
          __builtin_amdgcn_s_sleep(2);
        }
      }
      __syncthreads();
    }

    // ---- coherent fragment loads: h(t-1), this wave's k-slice ----
    const uint32_t* hrow =
        hsp + ((size_t)(rpar * NGRP + grp) * GB + (l & 15)) * NH;
    uint4 q[KTW][2];
#pragma unroll
    for (int kt = 0; kt < KTW; ++kt) {
      const uint32_t* p = hrow + kbase + kt * 32;
      q[kt][0] = ld_b128_coh(p);
      q[kt][1] = ld_b128_coh(p + 4);
    }
    asm volatile("s_waitcnt vmcnt(0)" ::: "memory");
    __builtin_amdgcn_sched_barrier(0);

    bf16x8 bh[KTW], bl[KTW];
#pragma unroll
    for (int kt = 0; kt < KTW; ++kt) {
      union { uint32_t u[4]; bf16x8 v; } H, L;
      H.u[0] = __builtin_amdgcn_perm(q[kt][0].y, q[kt][0].x, SEL_HI);
      L.u[0] = __builtin_amdgcn_perm(q[kt][0].y, q[kt][0].x, SEL_LO);
      H.u[1] = __builtin_amdgcn_perm(q[kt][0].w, q[kt][0].z, SEL_HI);
      L.u[1] = __builtin_amdgcn_perm(q[kt][0].w, q[kt][0].z, SEL_LO);
      H.u[2] = __builtin_amdgcn_perm(q[kt][1].y, q[kt][1].x, SEL_HI);
      L.u[2] = __builtin_amdgcn_perm(q[kt][1].y, q[kt][1].x, SEL_LO);
      H.u[3] = __builtin_amdgcn_perm(q[kt][1].w, q[kt][1].z, SEL_HI);
      L.u[3] = __builtin_amdgcn_perm(q[kt][1].w, q[kt][1].z, SEL_LO);
      bh[kt] = H.v; bl[kt] = L.v;
    }

    // ---- MFMA: 3-pass bf16 hi/lo split; w-hi streamed from LDS ----
    f32x4 acc[3];
#pragma unroll
    for (int g = 0; g < 3; ++g) acc[g] = (f32x4){0.f, 0.f, 0.f, 0.f};
#pragma unroll
    for (int kt = 0; kt < KTW; ++kt) {
#pragma unroll
      for (int g = 0; g < 3; ++g) {
        const bf16x8 whi =
            *(const bf16x8*)&wHs[(((g * WAVES + wv) * KTW + kt) * 64 + l) * 4];
        acc[g] = __builtin_amdgcn_mfma_f32_16x16x32_bf16(whi, bh[kt], acc[g], 0, 0, 0);
        acc[g] = __builtin_amdgcn_mfma_f32_16x16x32_bf16(whi, bl[kt], acc[g], 0, 0, 0);
        acc[g] = __builtin_amdgcn_mfma_f32_16x16x32_bf16(wlo[g][kt], bh[kt], acc[g], 0, 0, 0);
      }
    }

#pragma unroll
    for (int g = 0; g < 3; ++g)
#pragma unroll
      for (int qi = 0; qi < 4; ++qi)
        part[wv][g][(l >> 4) * 4 + qi][l & 15] = acc[g][qi];
    __syncthreads();   // barrier1: partials ready; orders h-reads before gating

    if (tid < 256) {
      float ghr = 0.f, ghz = 0.f, ghn = 0.f;
#pragma unroll
      for (int ww = 0; ww < WAVES; ++ww) {
        ghr += part[ww][0][jl][b];
        ghz += part[ww][1][jl][b];
        ghn += part[ww][2][jl][b];
      }
      const float r = 1.f / (1.f + expf(-(xr + ghr + bhr)));
      const float z = 1.f / (1.f + expf(-(xz + ghz + bhz)));
      const float n = tanhf(xn + r * (ghn + bhn));
      const float h = (1.f - z) * n + z * hprev;
      hprev = h;

      union { __bf16 f; uint16_t u; } hh, hl;
      hh.f = (__bf16)h;
      hl.f = (__bf16)(h - (float)hh.f);
      // step-exchange store first (critical path)
      st_b32_coh(hsp + ((size_t)(wpar * NGRP + grp) * GB + b) * NH + j,
                 ((uint32_t)hh.u << 16) | hl.u);
      // layer-handoff planes
      const size_t po = ((size_t)t * BATCH + n0 + b) * NH + j;
      ahi[po] = hh.f;
      alo[po] = hl.f;
    }

    __syncthreads();   // barrier2: full drain (vmcnt+lgkm before s_barrier)
    if (tid == 0) st_b32_coh(flg + grp * NBLK_G + blk_in,
                             (uint32_t)(fbase + t + 1));
  }
}

// ---------------------------------------------------------------------------
__global__ __launch_bounds__(256) void k_proj(
    const __bf16* __restrict__ ahi, const __bf16* __restrict__ alo,
    const float* __restrict__ wp, const float* __restrict__ bp,
    float* __restrict__ out) {
  int b = blockIdx.x;
  int f = threadIdx.x;
  __shared__ float hs[NH];
  __shared__ float red[FCD];

  const size_t base = ((size_t)(T_FRAMES - 1) * BATCH + b) * NH;
  for (int k = f; k < NH; k += FCD)
    hs[k] = (float)ahi[base + k] + (float)alo[base + k];
  __syncthreads();

  float acc = bp[f];
  const float* wrow = wp + (size_t)f * NH;
#pragma unroll 4
  for (int k = 0; k < NH; k += 4) {
    const float4 w4 = *(const float4*)&wrow[k];
    acc = fmaf(w4.x, hs[k], acc);
    acc = fmaf(w4.y, hs[k + 1], acc);
    acc = fmaf(w4.z, hs[k + 2], acc);
    acc = fmaf(w4.w, hs[k + 3], acc);
  }
  red[f] = acc * acc;
  __syncthreads();
  for (int s = FCD / 2; s > 0; s >>= 1) {
    if (f < s) red[f] += red[f + s];
    __syncthreads();
  }
  float nrm = sqrtf(red[0]);
  out[(size_t)b * FCD + f] = acc / fmaxf(nrm, 1e-12f);
}

// ---------------------------------------------------------------------------
extern "C" void kernel_launch(void* const* d_in, const int* in_sizes, int n_in,
                              void* d_out, int out_size, void* d_ws, size_t ws_size,
                              hipStream_t stream) {
  const float* x        = (const float*)d_in[0];
  const float* wih0     = (const float*)d_in[1];
  const float* whh0     = (const float*)d_in[2];
  const float* bih0     = (const float*)d_in[3];
  const float* bhh0     = (const float*)d_in[4];
  const float* wih_rest = (const float*)d_in[5];
  const float* whh_rest = (const float*)d_in[6];
  const float* bih_rest = (const float*)d_in[7];
  const float* bhh_rest = (const float*)d_in[8];
  const float* wp       = (const float*)d_in[9];
  const float* bp       = (const float*)d_in[10];
  float* out = (float*)d_out;

  // ---- workspace layout (bytes) ----
  const size_t ahi_b = (size_t)T_FRAMES * BATCH * NH * 2;    // 33,554,432
  const size_t whl_b = (size_t)2 * NG * NH * 2;              // 12,582,912/plane
  const size_t xT_b  = (size_t)T_FRAMES * NMELS * BATCH * 4; //  5,242,880
  const size_t hsp_b = (size_t)2 * NGRP * GB * NH * 4;       //    524,288
  const size_t flg_b = 4096;
  const size_t fixed = 2 * ahi_b + 2 * whl_b + xT_b + hsp_b + flg_b;

  char* wsb = (char*)d_ws;
  __bf16*    ahi  = (__bf16*)wsb;
  __bf16*    alo  = (__bf16*)(wsb + ahi_b);
  __bf16*    wchi = (__bf16*)(wsb + 2 * ahi_b);              // [2][NG][NH]
  __bf16*    wclo = (__bf16*)(wsb + 2 * ahi_b + whl_b);
  float*     xT   = (float*)(wsb + 2 * ahi_b + 2 * whl_b);
  uint32_t*  hsp  = (uint32_t*)(wsb + 2 * ahi_b + 2 * whl_b + xT_b);
  uint32_t*  flg  = (uint32_t*)(wsb + 2 * ahi_b + 2 * whl_b + xT_b + hsp_b);
  float*     xp   = (float*)(wsb + fixed);

  int Tc = 0;
  for (int c = T_FRAMES; c >= 2; c >>= 1) {
    if (fixed + (size_t)c * NG * BATCH * 4 <= ws_size) { Tc = c; break; }
  }
  if (Tc == 0) return;

  k_transpose_x<<<T_FRAMES, 256, 0, stream>>>(x, xT);
  k_wconv<<<(NG * NH) / 1024, 256, 0, stream>>>(wih_rest, wchi, wclo);
  k_wconv<<<(NG * NH) / 1024, 256, 0, stream>>>(
      wih_rest + (size_t)NG * NH, wchi + (size_t)NG * NH, wclo + (size_t)NG * NH);
  hipMemsetAsync(flg, 0, flg_b, stream);   // flags monotonic per launch

  for (int layer = 0; layer < 3; ++layer) {
    const float* whh; const float* bih; const float* bhh;
    if (layer == 0) {
      whh = whh0; bih = bih0; bhh = bhh0;
    } else {
      whh = whh_rest + (size_t)(layer - 1) * NG * NH;
      bih = bih_rest + (size_t)(layer - 1) * NG;
      bhh = bhh_rest + (size_t)(layer - 1) * NG;
    }
    hipMemsetAsync(hsp, 0, hsp_b, stream);   // h(-1) = 0 (both parities)
    const int fbase = layer * T_FRAMES;
    for (int c0 = 0; c0 < T_FRAMES; c0 += Tc) {
      if (layer == 0) {
        dim3 gg(NG / 64, Tc);
        k_gemm_xp<<<gg, 256, 0, stream>>>(xT, wih0, bih, xp, NMELS, c0);
      } else {
        const __bf16* whi_l = wchi + (size_t)(layer - 1) * NG * NH;
        const __bf16* wlo_l = wclo + (size_t)(layer - 1) * NG * NH;
        dim3 gg2(NG / 128, (Tc * BATCH) / 128);
        k_gemm_mfma2<<<gg2, 256, 0, stream>>>(
            whi_l, wlo_l,
            ahi + (size_t)c0 * BATCH * NH, alo + (size_t)c0 * BATCH * NH,
            bih, xp);
      }
      k_gru_layer<<<NBLK, 512, 0, stream>>>(xp, whh, bhh, ahi, alo,
                                            hsp, flg, c0, c0 + Tc, fbase);
    }
  }

  k_proj<<<BATCH, FCD, 0, stream>>>(ahi, alo, wp, bp, out);
}